// Round 2
// baseline (775.799 us; speedup 1.0000x reference)
//
#include <hip/hip_runtime.h>

#define NUM_FIELDS 10
#define VOCAB 100000
#define EMBED_DIM 16
#define BATCH 16384
#define NPAIRS 45
#define NITEMS (BATCH * NUM_FIELDS)   // 163,840
#define KBKT 1024                     // buckets/column; bucket = x>>7 (0..781)
#define IPT 4                         // items per thread in gather passes

typedef float v4f __attribute__((ext_vector_type(4)));

// triu(k=1) row-major pair tables
__device__ __constant__ unsigned char PI[NPAIRS] = {
    0,0,0,0,0,0,0,0,0, 1,1,1,1,1,1,1,1, 2,2,2,2,2,2,2,
    3,3,3,3,3,3, 4,4,4,4,4, 5,5,5,5, 6,6,6, 7,7, 8};
__device__ __constant__ unsigned char PJ[NPAIRS] = {
    1,2,3,4,5,6,7,8,9, 2,3,4,5,6,7,8,9, 3,4,5,6,7,8,9,
    4,5,6,7,8,9, 5,6,7,8,9, 6,7,8,9, 7,8,9, 8,9, 9};

// ---------------- sort pipeline (workspace layout) ----------------
// u32 hist  [10][KBKT]   @ ws + 0
// u32 cursor[10][KBKT]   @ ws + 10*KBKT
// u32 sorted[10][BATCH]  @ ws + 20*KBKT   (packed (x<<14)|b, 31 bits)
#define WS_WORDS (20 * KBKT + NUM_FIELDS * BATCH)

__global__ __launch_bounds__(256) void k_zero(unsigned int* __restrict__ ws) {
    int t = blockIdx.x * 256 + threadIdx.x;
    if (t < 10 * KBKT) ws[t] = 0;           // hist
}

__global__ __launch_bounds__(256) void k_hist(const int* __restrict__ x,
                                              unsigned int* __restrict__ ws) {
    int t = blockIdx.x * 256 + threadIdx.x;
    if (t >= NITEMS) return;
    int i = t % NUM_FIELDS;
    unsigned int xv = (unsigned int)x[t];
    atomicAdd(&ws[i * KBKT + (xv >> 7)], 1u);
}

__global__ __launch_bounds__(KBKT) void k_scan(unsigned int* __restrict__ ws) {
    __shared__ unsigned int s[KBKT];
    const int c = blockIdx.x;             // column 0..9
    const int k = threadIdx.x;
    unsigned int h = ws[c * KBKT + k];
    s[k] = h;
    __syncthreads();
    for (int off = 1; off < KBKT; off <<= 1) {
        unsigned int v = (k >= off) ? s[k - off] : 0u;
        __syncthreads();
        s[k] += v;
        __syncthreads();
    }
    // exclusive prefix -> cursor
    ws[10 * KBKT + c * KBKT + k] = s[k] - h;
}

__global__ __launch_bounds__(256) void k_scatter(const int* __restrict__ x,
                                                 unsigned int* __restrict__ ws) {
    int t = blockIdx.x * 256 + threadIdx.x;
    if (t >= NITEMS) return;
    int b = t / NUM_FIELDS;
    int i = t - b * NUM_FIELDS;
    unsigned int xv = (unsigned int)x[t];
    unsigned int pos = atomicAdd(&ws[10 * KBKT + i * KBKT + (xv >> 7)], 1u);
    ws[20 * KBKT + i * BATCH + pos] = (xv << 14) | (unsigned int)b;
}

// ---------------- gather passes ----------------
// Pass A: out[b][p] = emb[j][i*VOCAB + x_i], iterated in x_i-sorted order.
// Pass B: out[b][p] *= emb[i][j*VOCAB + x_j], iterated in x_j-sorted order.
// Thread layout: gtid -> d4 (lane%4), q = gtid>>2; tb = q & 4095; p = q>>12.
// Items t = tb + k*4096 (k<IPT): lanes 0..63 of a wave cover 16 CONSECUTIVE
// sorted positions -> each gather instruction reads ascending addresses in a
// ~6KB window of one emb plane (DRAM page locality + dup-index line hits).
__global__ __launch_bounds__(256) void k_passA(const unsigned int* __restrict__ ws,
                                               const float* __restrict__ emb,
                                               float* __restrict__ out) {
    const unsigned int* sorted = ws + 20 * KBKT;
    int gtid = blockIdx.x * 256 + threadIdx.x;
    const int d4 = gtid & 3;
    const int q  = gtid >> 2;
    const int tb = q & 4095;
    const int p  = q >> 12;
    if (p >= NPAIRS) return;
    const int i = PI[p], j = PJ[p];

    v4f r[IPT];
    unsigned int bb[IPT];
    #pragma unroll
    for (int k = 0; k < IPT; ++k) {
        const int t = tb + k * 4096;
        const unsigned int v = sorted[i * BATCH + t];
        bb[k] = v & 16383u;
        const unsigned int xv = v >> 14;
        const size_t row = ((size_t)j * (NUM_FIELDS * VOCAB)
                          + (size_t)i * VOCAB + xv) * EMBED_DIM;
        r[k] = *(const v4f*)(emb + row + (size_t)d4 * 4);
    }
    #pragma unroll
    for (int k = 0; k < IPT; ++k) {
        *((v4f*)out + (size_t)(bb[k] * NPAIRS + p) * 4 + d4) = r[k];
    }
}

__global__ __launch_bounds__(256) void k_passB(const unsigned int* __restrict__ ws,
                                               const float* __restrict__ emb,
                                               float* __restrict__ out) {
    const unsigned int* sorted = ws + 20 * KBKT;
    int gtid = blockIdx.x * 256 + threadIdx.x;
    const int d4 = gtid & 3;
    const int q  = gtid >> 2;
    const int tb = q & 4095;
    const int p  = q >> 12;
    if (p >= NPAIRS) return;
    const int i = PI[p], j = PJ[p];

    v4f r[IPT];
    unsigned int bb[IPT];
    #pragma unroll
    for (int k = 0; k < IPT; ++k) {
        const int t = tb + k * 4096;
        const unsigned int v = sorted[j * BATCH + t];
        bb[k] = v & 16383u;
        const unsigned int xv = v >> 14;
        const size_t row = ((size_t)i * (NUM_FIELDS * VOCAB)
                          + (size_t)j * VOCAB + xv) * EMBED_DIM;
        r[k] = *(const v4f*)(emb + row + (size_t)d4 * 4);
    }
    #pragma unroll
    for (int k = 0; k < IPT; ++k) {
        v4f* op = (v4f*)out + (size_t)(bb[k] * NPAIRS + p) * 4 + d4;
        *op = *op * r[k];
    }
}

// ---------------- fallback: R0 direct kernel ----------------
__device__ __constant__ unsigned short PAIR_IJ[NPAIRS] = {
    0x0100, 0x0200, 0x0300, 0x0400, 0x0500, 0x0600, 0x0700, 0x0800, 0x0900,
    0x0201, 0x0301, 0x0401, 0x0501, 0x0601, 0x0701, 0x0801, 0x0901,
    0x0302, 0x0402, 0x0502, 0x0602, 0x0702, 0x0802, 0x0902,
    0x0403, 0x0503, 0x0603, 0x0703, 0x0803, 0x0903,
    0x0504, 0x0604, 0x0704, 0x0804, 0x0904,
    0x0605, 0x0705, 0x0805, 0x0905,
    0x0706, 0x0806, 0x0906,
    0x0807, 0x0907,
    0x0908
};

__global__ __launch_bounds__(256) void ffm_pair_kernel(
        const int* __restrict__ x,
        const float* __restrict__ emb,
        float* __restrict__ out) {
    const int total  = BATCH * NPAIRS * 4;
    const int stride = total / 4;
    const int tid0   = blockIdx.x * blockDim.x + threadIdx.x;
    if (tid0 >= stride) return;
    v4f a[4], c[4];
    #pragma unroll
    for (int k = 0; k < 4; ++k) {
        const int tid = tid0 + k * stride;
        const int d4 = tid & 3;
        const int bp = tid >> 2;
        const int p  = bp % NPAIRS;
        const int b  = bp / NPAIRS;
        const unsigned int ij = PAIR_IJ[p];
        const int i = (int)(ij & 0xff);
        const int j = (int)(ij >> 8);
        const int xi = x[b * NUM_FIELDS + i] + i * VOCAB;
        const int xj = x[b * NUM_FIELDS + j] + j * VOCAB;
        const size_t rowA = ((size_t)j * (NUM_FIELDS * VOCAB) + (size_t)xi) * EMBED_DIM;
        const size_t rowB = ((size_t)i * (NUM_FIELDS * VOCAB) + (size_t)xj) * EMBED_DIM;
        a[k] = *(const v4f*)(emb + rowA + (size_t)d4 * 4);
        c[k] = *(const v4f*)(emb + rowB + (size_t)d4 * 4);
    }
    #pragma unroll
    for (int k = 0; k < 4; ++k) {
        const int tid = tid0 + k * stride;
        __builtin_nontemporal_store(a[k] * c[k], (v4f*)out + tid);
    }
}

extern "C" void kernel_launch(void* const* d_in, const int* in_sizes, int n_in,
                              void* d_out, int out_size, void* d_ws, size_t ws_size,
                              hipStream_t stream) {
    const int*   x   = (const int*)d_in[0];
    const float* emb = (const float*)d_in[1];
    float*       out = (float*)d_out;

    if (ws_size < (size_t)WS_WORDS * 4) {
        // workspace too small: fall back to direct random-gather kernel
        const int nthr = BATCH * NPAIRS;         // total/4
        ffm_pair_kernel<<<(nthr + 255) / 256, 256, 0, stream>>>(x, emb, out);
        return;
    }

    unsigned int* ws = (unsigned int*)d_ws;

    k_zero   <<<(10 * KBKT + 255) / 256, 256, 0, stream>>>(ws);
    k_hist   <<<(NITEMS + 255) / 256,     256, 0, stream>>>(x, ws);
    k_scan   <<<NUM_FIELDS, KBKT,              0, stream>>>(ws);
    k_scatter<<<(NITEMS + 255) / 256,     256, 0, stream>>>(x, ws);

    const int gthreads = NPAIRS * 4096 * 4;     // 737,280
    k_passA<<<(gthreads + 255) / 256, 256, 0, stream>>>(ws, emb, out);
    k_passB<<<(gthreads + 255) / 256, 256, 0, stream>>>(ws, emb, out);
}